// Round 25
// baseline (123.524 us; speedup 1.0000x reference)
//
#include <hip/hip_runtime.h>

#define T_LEN  4096
#define KS     16
#define NSEG   8           // T segments (512 output steps each)
#define SEG_CH 32          // output chunks per segment
#define WARM_CH 24         // 384 warm-up steps (geometry validated R17-R24)

#define ALPHA_F 0.9048374180359595f
#define BETA_F  0.09516258196404048f
#define THETA_F 0.5f

// Full-wave (64-lane) max, result in ALL lanes. Verbatim from the passing
// R3-R24 kernels (manual s_nop hazard handling inside asm).
__device__ __forceinline__ float wave64_max_all(float v) {
  float m, t;
  asm("s_nop 1\n\t"
      "v_max_f32 %0, %2, %2 quad_perm:[1,0,3,2] row_mask:0xf bank_mask:0xf\n\t"
      "s_nop 1\n\t"
      "v_max_f32 %0, %0, %0 quad_perm:[2,3,0,1] row_mask:0xf bank_mask:0xf\n\t"
      "s_nop 1\n\t"
      "v_max_f32 %0, %0, %0 row_half_mirror row_mask:0xf bank_mask:0xf\n\t"
      "s_nop 1\n\t"
      "v_max_f32 %0, %0, %0 row_mirror row_mask:0xf bank_mask:0xf\n\t"
      "v_mov_b32 %1, %0\n\t"
      "s_nop 1\n\t"
      "v_permlane32_swap_b32 %1, %0\n\t"
      "s_nop 1\n\t"
      "v_max_f32 %0, %0, %1\n\t"
      "v_mov_b32 %1, %0\n\t"
      "s_nop 1\n\t"
      "v_permlane16_swap_b32 %1, %0\n\t"
      "s_nop 1\n\t"
      "v_max_f32 %0, %0, %1"
      : "=&v"(m), "=&v"(t)
      : "v"(v));
  return m;
}

__global__ __launch_bounds__(64, 2)
void convlif_wta_kernel(const float* __restrict__ x, const float* __restrict__ W,
                        float* __restrict__ out) {
  const int blk  = blockIdx.x;
  const int b    = blk >> 3;          // batch
  const int seg  = blk & (NSEG - 1);  // time segment
  const int lane = threadIdx.x;       // channel k

  const int cout0  = seg * SEG_CH;                                  // first output chunk
  const int cstart = (cout0 > WARM_CH) ? (cout0 - WARM_CH) : 0;     // warm-up start
  const int cend   = cout0 + SEG_CH;

  // per-lane conv weights W[k][0..15] (verbatim)
  float w[KS];
  {
    const float4* w4 = reinterpret_cast<const float4*>(W + lane * KS);
    #pragma unroll
    for (int q = 0; q < 4; ++q) {
      float4 a = w4[q];
      w[4*q+0] = a.x; w[4*q+1] = a.y; w[4*q+2] = a.z; w[4*q+3] = a.w;
    }
  }

  const float4* xv4 = reinterpret_cast<const float4*>(x + (size_t)b * T_LEN);
  float* orow = out + ((size_t)(b * 64 + lane)) * T_LEN;   // this lane's channel row

  float uA[16], uB[16];    // u double-buffer (cur / next chunk)
  float xwA[32], xwB[32];  // x-window double-buffer; window(k) = x[16k-16..16k+15]

  // window(k) load, k >= 1 (quads 4k-4 .. 4k+3)
  auto load_win = [&](float (&dst)[32], int k) {
    const int b4 = 4 * k - 4;
    #pragma unroll
    for (int q = 0; q < 8; ++q) {
      float4 a = xv4[b4 + q];
      dst[4*q+0] = a.x; dst[4*q+1] = a.y; dst[4*q+2] = a.z; dst[4*q+3] = a.w;
    }
  };

  float v = 0.0f;   // exact for seg 0 (no warm); speculative else (validated)

  // prologue: conv(cstart) -> uA; xwA = window(cstart+1)
  {
    float xf0[32];
    if (cstart == 0) {
      #pragma unroll
      for (int m = 0; m < 16; ++m) xf0[m] = 0.0f;
      #pragma unroll
      for (int q = 0; q < 4; ++q) {
        float4 a = xv4[q];
        xf0[16+4*q+0] = a.x; xf0[16+4*q+1] = a.y;
        xf0[16+4*q+2] = a.z; xf0[16+4*q+3] = a.w;
      }
    } else {
      load_win(xf0, cstart);
    }
    #pragma unroll
    for (int i = 0; i < 16; ++i) {
      float acc = w[0] * xf0[1 + i];
      #pragma unroll
      for (int j = 1; j < KS; ++j) acc = fmaf(w[j], xf0[1 + i + j], acc);
      uA[i] = BETA_F * acc;
    }
    load_win(xwA, cstart + 1);
  }

  // fused chunk, warm variant: LIF(c) from cur; conv(c+1) from curw -> nxt;
  // loads window(c+2) -> nxtw. Conv FMAs are independent of the LIF chain and
  // textually precede each step's ballot -> scheduler fills chain stalls.
  auto fused_warm = [&](float (&cur)[16], float (&nxt)[16],
                        float (&curw)[32], float (&nxtw)[32], int c) {
    {
      int k = c + 2; if (k > cend - 1) k = cend - 1;   // clamp (tail waste ~2%)
      load_win(nxtw, k);
    }
    #pragma unroll
    for (int i = 0; i < 16; ++i) {
      // conv output i of chunk c+1 (verbatim summation order)
      float acc = w[0] * curw[1 + i];
      #pragma unroll
      for (int j = 1; j < KS; ++j) acc = fmaf(w[j], curw[1 + i + j], acc);
      nxt[i] = BETA_F * acc;
      // LIF step i of chunk c (verbatim blind-apply + rare repair)
      float vr = fmaf(ALPHA_F, v, cur[i]);
      float vm = vr - THETA_F;
      unsigned long long sp = __ballot(vr >= THETA_F);
      bool c1 = (vr >= THETA_F);
      v = c1 ? vm : vr;
      if (__builtin_expect((sp & (sp - 1ull)) != 0ull, 0)) {
        float m = wave64_max_all(vr);
        unsigned long long eq = __ballot(vr == m);
        bool win = (lane == __builtin_ctzll(eq));
        v = win ? vm : vr;
      }
    }
  };

  // fused chunk, output variant: + sv + coalesced store
  auto fused_out = [&](float (&cur)[16], float (&nxt)[16],
                       float (&curw)[32], float (&nxtw)[32], int c) {
    {
      int k = c + 2; if (k > cend - 1) k = cend - 1;
      load_win(nxtw, k);
    }
    float sv[16];
    #pragma unroll
    for (int i = 0; i < 16; ++i) {
      float acc = w[0] * curw[1 + i];
      #pragma unroll
      for (int j = 1; j < KS; ++j) acc = fmaf(w[j], curw[1 + i + j], acc);
      nxt[i] = BETA_F * acc;

      float vr = fmaf(ALPHA_F, v, cur[i]);
      float vm = vr - THETA_F;
      unsigned long long sp = __ballot(vr >= THETA_F);
      bool c1 = (vr >= THETA_F);
      sv[i] = c1 ? 1.0f : 0.0f;
      v     = c1 ? vm : vr;
      if (__builtin_expect((sp & (sp - 1ull)) != 0ull, 0)) {
        float m = wave64_max_all(vr);
        unsigned long long eq = __ballot(vr == m);
        bool win = (lane == __builtin_ctzll(eq));
        sv[i] = win ? 1.0f : 0.0f;
        v     = win ? vm : vr;
      }
    }
    float4* p = reinterpret_cast<float4*>(orow + (size_t)c * 16);
    p[0] = make_float4(sv[0],  sv[1],  sv[2],  sv[3]);
    p[1] = make_float4(sv[4],  sv[5],  sv[6],  sv[7]);
    p[2] = make_float4(sv[8],  sv[9],  sv[10], sv[11]);
    p[3] = make_float4(sv[12], sv[13], sv[14], sv[15]);
  };

  // warm phase (count 0 or 24 — even; buffer roles return to A at phase end)
  for (int c = cstart; c < cout0; c += 2) {
    fused_warm(uA, uB, xwA, xwB, c);
    fused_warm(uB, uA, xwB, xwA, c + 1);
  }
  // output phase (count 32 — even)
  for (int c = cout0; c < cend; c += 2) {
    fused_out(uA, uB, xwA, xwB, c);
    fused_out(uB, uA, xwB, xwA, c + 1);
  }
}

extern "C" void kernel_launch(void* const* d_in, const int* in_sizes, int n_in,
                              void* d_out, int out_size, void* d_ws, size_t ws_size,
                              hipStream_t stream) {
  const float* x   = (const float*)d_in[0];
  const float* W   = (const float*)d_in[1];
  float*       out = (float*)d_out;
  convlif_wta_kernel<<<dim3(256 * NSEG), dim3(64), 0, stream>>>(x, W, out);
}

// Round 26
// 106.061 us; speedup vs baseline: 1.1647x; 1.1647x over previous
//
#include <hip/hip_runtime.h>

#define T_LEN  4096
#define KS     16
#define NSEG   8           // T segments (512 output steps each)
#define SEG_CH 32          // output chunks per segment
#define WARM_CH 20         // 320 warm-up steps (trim from validated 384; fork pre-committed)
#define USTRIDE 18         // u-row stride in dwords: 2-way bank aliasing, 8B-aligned

#define ALPHA_F 0.9048374180359595f
#define BETA_F  0.09516258196404048f
#define THETA_F 0.5f

// Full-wave (64-lane) max, result in ALL lanes. Verbatim from the passing
// R3-R25 kernels (manual s_nop hazard handling inside asm).
__device__ __forceinline__ float wave64_max_all(float v) {
  float m, t;
  asm("s_nop 1\n\t"
      "v_max_f32 %0, %2, %2 quad_perm:[1,0,3,2] row_mask:0xf bank_mask:0xf\n\t"
      "s_nop 1\n\t"
      "v_max_f32 %0, %0, %0 quad_perm:[2,3,0,1] row_mask:0xf bank_mask:0xf\n\t"
      "s_nop 1\n\t"
      "v_max_f32 %0, %0, %0 row_half_mirror row_mask:0xf bank_mask:0xf\n\t"
      "s_nop 1\n\t"
      "v_max_f32 %0, %0, %0 row_mirror row_mask:0xf bank_mask:0xf\n\t"
      "v_mov_b32 %1, %0\n\t"
      "s_nop 1\n\t"
      "v_permlane32_swap_b32 %1, %0\n\t"
      "s_nop 1\n\t"
      "v_max_f32 %0, %0, %1\n\t"
      "v_mov_b32 %1, %0\n\t"
      "s_nop 1\n\t"
      "v_permlane16_swap_b32 %1, %0\n\t"
      "s_nop 1\n\t"
      "v_max_f32 %0, %0, %1"
      : "=&v"(m), "=&v"(t)
      : "v"(v));
  return m;
}

__global__ __launch_bounds__(128, 4)
void convlif_wta_kernel(const float* __restrict__ x, const float* __restrict__ W,
                        float* __restrict__ out) {
  const int blk  = blockIdx.x;
  const int b    = blk >> 3;          // batch
  const int seg  = blk & (NSEG - 1);  // time segment
  const int wave = threadIdx.x >> 6;  // 0 = consumer (LIF), 1 = producer (conv)
  const int lane = threadIdx.x & 63;  // channel k

  const int cout0  = seg * SEG_CH;                                  // first output chunk
  const int cstart = (cout0 > WARM_CH) ? (cout0 - WARM_CH) : 0;     // warm-up start
  const int cend   = cout0 + SEG_CH;
  const int wpairs = (cout0 - cstart) >> 1;  // 10 (seg>0) or 0 (seg 0)
  const int npair  = (cend - cstart) >> 1;   // 26 (seg>0) or 16 (seg 0)

  // u handoff ring: [slot][chunk-of-pair][lane][i]; stride 18 dwords ->
  // float2 8B-aligned, 2-way bank aliasing (free). 18 KB/block -> 8 blocks/CU.
  __shared__ float dbuf[2][2][64][USTRIDE];

  const float4* xv4 = reinterpret_cast<const float4*>(x + (size_t)b * T_LEN);
  float* orow = out + ((size_t)(b * 64 + lane)) * T_LEN;   // this lane's channel row

  if (wave == 1) {
    // ================= producer: conv pairs into the LDS ring =============
    // (verbatim R24; barrier count = npair + 1, matching the consumer)
    float w[KS];
    {
      const float4* w4 = reinterpret_cast<const float4*>(W + lane * KS);
      #pragma unroll
      for (int q = 0; q < 4; ++q) {
        float4 a = w4[q];
        w[4*q+0] = a.x; w[4*q+1] = a.y; w[4*q+2] = a.z; w[4*q+3] = a.w;
      }
    }

    for (int p = 0; p < npair; ++p) {
      #pragma unroll
      for (int ch = 0; ch < 2; ++ch) {
        const int c = cstart + 2 * p + ch;
        // conv for chunk c — verbatim summation order of all passing rounds
        float xf[32];
        if (c == 0) {
          #pragma unroll
          for (int m = 0; m < 16; ++m) xf[m] = 0.0f;
        } else {
          const int b4 = 4 * c - 4;
          #pragma unroll
          for (int q = 0; q < 4; ++q) {
            float4 a = xv4[b4 + q];
            xf[4*q+0] = a.x; xf[4*q+1] = a.y; xf[4*q+2] = a.z; xf[4*q+3] = a.w;
          }
        }
        #pragma unroll
        for (int q = 0; q < 4; ++q) {
          float4 a = xv4[4*c + q];
          xf[16+4*q+0] = a.x; xf[16+4*q+1] = a.y;
          xf[16+4*q+2] = a.z; xf[16+4*q+3] = a.w;
        }

        float* ur = &dbuf[p & 1][ch][lane][0];
        #pragma unroll
        for (int i = 0; i < 16; i += 2) {
          float acc0 = w[0] * xf[1 + i];
          #pragma unroll
          for (int j = 1; j < KS; ++j) acc0 = fmaf(w[j], xf[1 + i + j], acc0);
          float acc1 = w[0] * xf[2 + i];
          #pragma unroll
          for (int j = 1; j < KS; ++j) acc1 = fmaf(w[j], xf[2 + i + j], acc1);
          *reinterpret_cast<float2*>(ur + i) =
              make_float2(BETA_F * acc0, BETA_F * acc1);   // u[i], u[i+1]
        }
      }
      __syncthreads();   // pair p published; consumer reads it next interval
    }
    __syncthreads();     // final interval (consumer consumes last pair)
  } else {
    // ================= consumer: serial LIF + WTA over pairs ==============
    // Pipelined one pair behind the producer. Phase split (static): warm
    // pairs run a LEAN body (no sv, no store — identical state arithmetic);
    // output pairs run the full verbatim R24 body. Barriers: 1 + npair.
    float v = 0.0f;      // exact for seg 0 (no warm); speculative else

    __syncthreads();     // interval 0: producer fills pair 0

    // ---- warm pairs (lean: state only) ----
    for (int q = 0; q < wpairs; ++q) {
      const int slot = q & 1;
      #pragma unroll
      for (int ch = 0; ch < 2; ++ch) {
        float u[16];
        {
          const float* ur = &dbuf[slot][ch][lane][0];
          #pragma unroll
          for (int i = 0; i < 16; i += 2) {
            float2 t2 = *reinterpret_cast<const float2*>(ur + i);
            u[i] = t2.x; u[i + 1] = t2.y;
          }
        }
        #pragma unroll
        for (int i = 0; i < 16; ++i) {
          float vr = fmaf(ALPHA_F, v, u[i]);
          float vm = vr - THETA_F;
          unsigned long long sp = __ballot(vr >= THETA_F);
          bool c1 = (vr >= THETA_F);
          v = c1 ? vm : vr;
          if (__builtin_expect((sp & (sp - 1ull)) != 0ull, 0)) {
            float m = wave64_max_all(vr);
            unsigned long long eq = __ballot(vr == m);
            bool win = (lane == __builtin_ctzll(eq));
            v = win ? vm : vr;
          }
        }
      }
      __syncthreads();
    }

    // ---- output pairs (full body + store) ----
    for (int q = wpairs; q < npair; ++q) {
      const int slot = q & 1;
      #pragma unroll
      for (int ch = 0; ch < 2; ++ch) {
        const int c = cstart + 2 * q + ch;
        float u[16];
        {
          const float* ur = &dbuf[slot][ch][lane][0];
          #pragma unroll
          for (int i = 0; i < 16; i += 2) {
            float2 t2 = *reinterpret_cast<const float2*>(ur + i);
            u[i] = t2.x; u[i + 1] = t2.y;
          }
        }
        float sv[16];
        #pragma unroll
        for (int i = 0; i < 16; ++i) {
          float vr = fmaf(ALPHA_F, v, u[i]);
          float vm = vr - THETA_F;
          unsigned long long sp = __ballot(vr >= THETA_F);
          bool c1 = (vr >= THETA_F);
          sv[i] = c1 ? 1.0f : 0.0f;
          v     = c1 ? vm : vr;
          if (__builtin_expect((sp & (sp - 1ull)) != 0ull, 0)) {
            float m = wave64_max_all(vr);
            unsigned long long eq = __ballot(vr == m);
            bool win = (lane == __builtin_ctzll(eq));
            sv[i] = win ? 1.0f : 0.0f;
            v     = win ? vm : vr;
          }
        }
        float4* pp = reinterpret_cast<float4*>(orow + (size_t)c * 16);
        pp[0] = make_float4(sv[0],  sv[1],  sv[2],  sv[3]);
        pp[1] = make_float4(sv[4],  sv[5],  sv[6],  sv[7]);
        pp[2] = make_float4(sv[8],  sv[9],  sv[10], sv[11]);
        pp[3] = make_float4(sv[12], sv[13], sv[14], sv[15]);
      }
      __syncthreads();
    }
  }
}

extern "C" void kernel_launch(void* const* d_in, const int* in_sizes, int n_in,
                              void* d_out, int out_size, void* d_ws, size_t ws_size,
                              hipStream_t stream) {
  const float* x   = (const float*)d_in[0];
  const float* W   = (const float*)d_in[1];
  float*       out = (float*)d_out;
  convlif_wta_kernel<<<dim3(256 * NSEG), dim3(128), 0, stream>>>(x, W, out);
}